// Round 5
// baseline (131.206 us; speedup 1.0000x reference)
//
#include <hip/hip_runtime.h>
#include <stdint.h>

#define XC 4096      // CB*BS
#define MT 256       // batch rows per workgroup (main path)
#define NNZ 13       // nnz blocks per row block (setup guarantees)

typedef __attribute__((ext_vector_type(8))) short short8;
typedef __attribute__((ext_vector_type(4))) float f32x4;

static __device__ __forceinline__ unsigned short f2bf(float f) {
    union { float f; unsigned int u; } c; c.f = f;
    unsigned int u = c.u;
    unsigned int r = 0x7FFFu + ((u >> 16) & 1u);
    return (unsigned short)((u + r) >> 16);
}
static __device__ __forceinline__ unsigned int pk2(float a, float b) {
    return (unsigned int)f2bf(a) | ((unsigned int)f2bf(b) << 16);
}

// ---- prep: x fp32 -> bf16, w*mask fp32 -> bf16 (fused, one launch) ----
__global__ void prep(const float* __restrict__ x, const float* __restrict__ w,
                     const float* __restrict__ m, unsigned short* __restrict__ xbf,
                     unsigned short* __restrict__ wbf, int nx4, int nw4) {
    int i = blockIdx.x * 256 + threadIdx.x;
    if (i < nx4) {
        float4 a = ((const float4*)x)[i];
        ((uint2*)xbf)[i] = make_uint2(pk2(a.x, a.y), pk2(a.z, a.w));
    } else {
        int k = i - nx4;
        if (k < nw4) {
            float4 a = ((const float4*)w)[k];
            float4 b = ((const float4*)m)[k];
            ((uint2*)wbf)[k] = make_uint2(pk2(a.x * b.x, a.y * b.y),
                                          pk2(a.z * b.z, a.w * b.w));
        }
    }
}

// ---- main: LDS-free, register-pipelined MFMA ----
// grid = 128 r-blocks * 8 batch tiles; 4 waves; wave owns 64 batch rows.
// Each lane loads its MFMA A-fragment DIRECTLY from bf16 xbf (one aligned
// 16B load per mi): a wave instruction touches 16 rows x 64B contiguous,
// each 64B segment fully consumed by its 4 quads -> L2-sector efficient.
// w-frags streamed 2-deep (used only at their own iteration). No LDS,
// no ds ops, no manual waitcnt: compiler emits exact counted vmcnt for
// register-destination loads. 2-deep software pipeline in named regs.
// XCD mapping: mt = bx & 7 pins one batch tile per XCD -> 2.1 MB xbf
// slice is L2-resident, 13x chunk reuse hits L2.
__global__ __launch_bounds__(256, 3) void bsl_mfma3(
    const unsigned short* __restrict__ xbf, const int* __restrict__ cols,
    const unsigned short* __restrict__ wbf, const float* __restrict__ bias,
    float* __restrict__ out)
{
    const int tid  = threadIdx.x;
    const int bx   = blockIdx.x;
    const int mt   = bx & 7;      // XCD-pinned batch tile (grid = 128*8)
    const int r    = bx >> 3;
    const int row0 = mt * MT;
    const int start = r * NNZ;

    const int lane = tid & 63;
    const int wv   = tid >> 6;
    const int l15  = lane & 15;
    const int quad = lane >> 4;

    int cseq[NNZ];
    #pragma unroll
    for (int nn = 0; nn < NNZ; ++nn) cseq[nn] = cols[start + nn];

    // A-frag base: row (row0w + mi*16 + l15), cols c*32 + quad*8 .. +7
    const int row0w = row0 + wv * 64;
    const unsigned short* abase = xbf + ((size_t)row0w + l15) * XC + quad * 8;
    // B-frag base: lane holds w[o = l15 (+16 for h=1)][k = quad*8 + j]
    const unsigned short* wbase = wbf + (size_t)start * 1024 + l15 * 32 + quad * 8;

    f32x4 acc[4][2];
    #pragma unroll
    for (int i = 0; i < 4; ++i)
        #pragma unroll
        for (int j = 0; j < 2; ++j)
            acc[i][j] = (f32x4){0.f, 0.f, 0.f, 0.f};

    short8 ax[2][4];   // 2-deep stage: chunk parity x 4 mi fragments
    short8 wx[2][2];   // 2-deep stage: chunk parity x 2 output halves

    // prologue: issue loads for chunks 0 and 1
    #pragma unroll
    for (int p = 0; p < 2; ++p) {
        const unsigned short* ap = abase + (size_t)cseq[p] * 32;
        #pragma unroll
        for (int mi = 0; mi < 4; ++mi)
            ax[p][mi] = *(const short8*)(ap + (size_t)mi * 16 * XC);
        wx[p][0] = *(const short8*)(wbase + p * 1024);
        wx[p][1] = *(const short8*)(wbase + p * 1024 + 512);
    }

    #pragma unroll
    for (int nn = 0; nn < NNZ; ++nn) {
        const int cur = nn & 1;   // compile-time after unroll
        #pragma unroll
        for (int mi = 0; mi < 4; ++mi) {
            acc[mi][0] = __builtin_amdgcn_mfma_f32_16x16x32_bf16(ax[cur][mi], wx[cur][0], acc[mi][0], 0, 0, 0);
            acc[mi][1] = __builtin_amdgcn_mfma_f32_16x16x32_bf16(ax[cur][mi], wx[cur][1], acc[mi][1], 0, 0, 0);
        }
        // refill this parity slot with chunk nn+2 (regs free after the
        // MFMAs above issue; scoreboard handles the WAR)
        if (nn + 2 < NNZ) {
            const int p = nn + 2;
            const unsigned short* ap = abase + (size_t)cseq[p] * 32;
            #pragma unroll
            for (int mi = 0; mi < 4; ++mi)
                ax[cur][mi] = *(const short8*)(ap + (size_t)mi * 16 * XC);
            wx[cur][0] = *(const short8*)(wbase + p * 1024);
            wx[cur][1] = *(const short8*)(wbase + p * 1024 + 512);
        }
    }

    // epilogue: C/D layout col=l15(=o), row=quad*4+reg(=m)
    const float b0v = bias[r * 32 + l15];
    const float b1v = bias[r * 32 + 16 + l15];
    #pragma unroll
    for (int mi = 0; mi < 4; ++mi) {
        const int rbase = row0 + wv * 64 + mi * 16 + quad * 4;
        #pragma unroll
        for (int reg = 0; reg < 4; ++reg) {
            float* op = out + (size_t)(rbase + reg) * XC + r * 32;
            op[l15]      = acc[mi][0][reg] + b0v;
            op[16 + l15] = acc[mi][1][reg] + b1v;
        }
    }
}

// ---- fallback (ws too small / unexpected shape): inline-conversion kernel ----
__global__ __launch_bounds__(256, 3) void bsl_fallback(
    const float* __restrict__ x, const int* __restrict__ crow,
    const int* __restrict__ cols, const float* __restrict__ wf,
    const float* __restrict__ mf, const float* __restrict__ bias,
    float* __restrict__ out)
{
    __shared__ unsigned short w_lds[NNZ][32][40];
    __shared__ unsigned short x_lds[MT][40];

    const int tid = threadIdx.x;
    const int bx  = blockIdx.x;
    const int r   = bx & 127;
    const int mt  = bx >> 7;
    const int row0 = mt * MT;
    const int start = crow[r];
    const int nnzr  = crow[r + 1] - start;

    const float4* wsrc = (const float4*)(wf + (size_t)start * 1024);
    const float4* msrc = (const float4*)(mf + (size_t)start * 1024);
    for (int i = tid; i < nnzr * 256; i += 256) {
        int nn = i >> 8, rem = i & 255;
        int o = rem >> 3, sg = rem & 7;
        float4 a = wsrc[i], b = msrc[i];
        *(uint2*)&w_lds[nn][o][sg * 4] =
            make_uint2(pk2(a.x * b.x, a.y * b.y), pk2(a.z * b.z, a.w * b.w));
    }

    const int lane = tid & 63;
    const int wv   = tid >> 6;
    const int l15  = lane & 15;
    const int quad = lane >> 4;

    f32x4 acc[4][2];
    #pragma unroll
    for (int i = 0; i < 4; ++i)
        #pragma unroll
        for (int j = 0; j < 2; ++j)
            acc[i][j] = (f32x4){0.f, 0.f, 0.f, 0.f};

    const int s4 = tid & 7;
    const int rr = tid >> 3;
    float4 v[8];
    {
        int c = cols[start];
        const float* xb = x + (size_t)(row0 + rr) * XC + c * 32 + s4 * 4;
        #pragma unroll
        for (int j = 0; j < 8; ++j) v[j] = *(const float4*)(xb + (size_t)j * 32 * XC);
    }

    for (int nn = 0; nn < nnzr; ++nn) {
        __syncthreads();
        #pragma unroll
        for (int j = 0; j < 8; ++j)
            *(uint2*)&x_lds[rr + j * 32][s4 * 4] =
                make_uint2(pk2(v[j].x, v[j].y), pk2(v[j].z, v[j].w));
        __syncthreads();

        if (nn + 1 < nnzr) {
            int c = cols[start + nn + 1];
            const float* xb = x + (size_t)(row0 + rr) * XC + c * 32 + s4 * 4;
            #pragma unroll
            for (int j = 0; j < 8; ++j) v[j] = *(const float4*)(xb + (size_t)j * 32 * XC);
        }

        short8 b0 = *(const short8*)&w_lds[nn][l15][quad * 8];
        short8 b1 = *(const short8*)&w_lds[nn][16 + l15][quad * 8];
        #pragma unroll
        for (int mi = 0; mi < 4; ++mi) {
            short8 a = *(const short8*)&x_lds[wv * 64 + mi * 16 + l15][quad * 8];
            acc[mi][0] = __builtin_amdgcn_mfma_f32_16x16x32_bf16(a, b0, acc[mi][0], 0, 0, 0);
            acc[mi][1] = __builtin_amdgcn_mfma_f32_16x16x32_bf16(a, b1, acc[mi][1], 0, 0, 0);
        }
    }

    const float b0v = bias[r * 32 + l15];
    const float b1v = bias[r * 32 + 16 + l15];
    #pragma unroll
    for (int mi = 0; mi < 4; ++mi) {
        const int rbase = row0 + wv * 64 + mi * 16 + quad * 4;
        #pragma unroll
        for (int reg = 0; reg < 4; ++reg) {
            float* op = out + (size_t)(rbase + reg) * XC + r * 32;
            op[l15]      = acc[mi][0][reg] + b0v;
            op[16 + l15] = acc[mi][1][reg] + b1v;
        }
    }
}

extern "C" void kernel_launch(void* const* d_in, const int* in_sizes, int n_in,
                              void* d_out, int out_size, void* d_ws, size_t ws_size,
                              hipStream_t stream) {
    const float* x      = (const float*)d_in[0];
    const int*   crow   = (const int*)d_in[1];
    const int*   cols   = (const int*)d_in[2];
    const float* mask   = (const float*)d_in[3];
    const float* weight = (const float*)d_in[4];
    const float* bias   = (const float*)d_in[5];
    float* out = (float*)d_out;

    const int xel   = in_sizes[0];        // 2048*4096
    const int wel   = in_sizes[4];        // 1664*1024
    const int rb    = in_sizes[1] - 1;    // 128
    const int batch = xel / XC;           // 2048

    const size_t xb_bytes = (size_t)xel * 2;
    const size_t wb_bytes = (size_t)wel * 2;

    // fast path requires batch == 2048 (mt = bx & 7 mapping assumes 8 tiles)
    const bool fast = (ws_size >= xb_bytes + wb_bytes) && (rb == 128) &&
                      (in_sizes[2] == rb * NNZ) && (batch == MT * 8);

    if (fast) {
        unsigned short* xbf = (unsigned short*)d_ws;
        unsigned short* wbf = (unsigned short*)((char*)d_ws + xb_bytes);
        int nx4 = xel / 4, nw4 = wel / 4;
        int tot = nx4 + nw4;
        prep<<<dim3((tot + 255) / 256), dim3(256), 0, stream>>>(x, weight, mask,
                                                                xbf, wbf, nx4, nw4);
        bsl_mfma3<<<dim3(rb * (batch / MT)), dim3(256), 0, stream>>>(xbf, cols, wbf,
                                                                     bias, out);
    } else {
        bsl_fallback<<<dim3(rb * (batch / MT)), dim3(256), 0, stream>>>(
            x, crow, cols, weight, mask, bias, out);
    }
}

// Round 6
// 123.760 us; speedup vs baseline: 1.0602x; 1.0602x over previous
//
#include <hip/hip_runtime.h>
#include <stdint.h>

#define XC 4096      // CB*BS
#define MT 256       // batch rows per workgroup (main path)
#define NNZ 13       // nnz blocks per row block (setup guarantees)

typedef __attribute__((ext_vector_type(8))) short short8;
typedef __attribute__((ext_vector_type(4))) float f32x4;

static __device__ __forceinline__ unsigned short f2bf(float f) {
    union { float f; unsigned int u; } c; c.f = f;
    unsigned int u = c.u;
    unsigned int r = 0x7FFFu + ((u >> 16) & 1u);
    return (unsigned short)((u + r) >> 16);
}
static __device__ __forceinline__ unsigned int pk2(float a, float b) {
    return (unsigned int)f2bf(a) | ((unsigned int)f2bf(b) << 16);
}

// async global->LDS, 16B per lane; LDS dest = uniform base + lane*16
#define GLD_LDS16(g, l) __builtin_amdgcn_global_load_lds(                      \
    (const __attribute__((address_space(1))) void*)(g),                        \
    (__attribute__((address_space(3))) void*)(l), 16, 0, 0)

// ---- prep: x fp32 -> bf16, w*mask fp32 -> bf16 (fused, one launch) ----
__global__ void prep(const float* __restrict__ x, const float* __restrict__ w,
                     const float* __restrict__ m, unsigned short* __restrict__ xbf,
                     unsigned short* __restrict__ wbf, int nx4, int nw4) {
    int i = blockIdx.x * 256 + threadIdx.x;
    if (i < nx4) {
        float4 a = ((const float4*)x)[i];
        ((uint2*)xbf)[i] = make_uint2(pk2(a.x, a.y), pk2(a.z, a.w));
    } else {
        int k = i - nx4;
        if (k < nw4) {
            float4 a = ((const float4*)w)[k];
            float4 b = ((const float4*)m)[k];
            ((uint2*)wbf)[k] = make_uint2(pk2(a.x * b.x, a.y * b.y),
                                          pk2(a.z * b.z, a.w * b.w));
        }
    }
}

// ---- main: barrier-free wave-private pipeline, depth 4 ----
// grid = 128 r-blocks * 8 batch tiles; 4 waves; wave owns 64 batch rows.
// w frags in VGPRs; x chunks QUAD-buffered in wave-private LDS via
// global_load_lds; sync = s_waitcnt vmcnt(N) only. Depth 3 -> 4 gives
// 4 iterations of latency slack per chunk (steady wait vmcnt(12)).
// LDS 64 KiB * 2 blocks/CU = 128 <= 160 KiB, residency unchanged.
// XCD mapping: mt = bx & 7 pins one batch tile per XCD -> 2.1 MB xbf
// slice is L2-resident, 13x chunk reuse hits L2.
__global__ __launch_bounds__(256, 2) void bsl_mfma2(
    const unsigned short* __restrict__ xbf, const int* __restrict__ cols,
    const unsigned short* __restrict__ wbf, const float* __restrict__ bias,
    float* __restrict__ out)
{
    // 4 waves * 4 bufs * (64 rows * 32 shorts) = 64 KiB, XOR-swizzled
    __shared__ __align__(16) unsigned short x_lds[4 * 4 * 2048];

    const int tid  = threadIdx.x;
    const int bx   = blockIdx.x;
    const int mt   = bx & 7;      // XCD-pinned batch tile (grid = 128*8)
    const int r    = bx >> 3;
    const int row0 = mt * MT;
    const int start = r * NNZ;

    const int lane = tid & 63;
    const int wv   = tid >> 6;
    const int l15  = lane & 15;
    const int quad = lane >> 4;

    int cseq[NNZ];
    #pragma unroll
    for (int nn = 0; nn < NNZ; ++nn) cseq[nn] = cols[start + nn];

    // B frags: lane holds w[o = l15 (+16)][k = quad*8 + j]; coalesced 16B loads
    short8 wfrag[NNZ][2];
    {
        const unsigned short* wp0 = wbf + (size_t)start * 1024 + l15 * 32 + quad * 8;
        #pragma unroll
        for (int nn = 0; nn < NNZ; ++nn) {
            wfrag[nn][0] = *(const short8*)(wp0 + nn * 1024);
            wfrag[nn][1] = *(const short8*)(wp0 + nn * 1024 + 512);
        }
    }

    // staging geometry: lane covers row (j*16 + lane>>2), 16B unit
    // q = (lane&3) ^ ((lane>>3)&3)  (XOR swizzle; dest = base + lane*16)
    const int row0w = row0 + wv * 64;
    const int rl    = lane >> 2;
    const int qsw   = (lane & 3) ^ ((lane >> 3) & 3);
    const unsigned short* xsrc = xbf + ((size_t)row0w + rl) * XC + qsw * 8;
    unsigned short* lbase = &x_lds[wv * 8192];

    #pragma unroll
    for (int p = 0; p < 4; ++p) {   // issue chunks 0..3
        const unsigned short* g = xsrc + cseq[p] * 32;
        #pragma unroll
        for (int j = 0; j < 4; ++j)
            GLD_LDS16(g + (size_t)j * 16 * XC, lbase + p * 2048 + j * 512);
    }

    f32x4 acc[4][2];
    #pragma unroll
    for (int i = 0; i < 4; ++i)
        #pragma unroll
        for (int j = 0; j < 2; ++j)
            acc[i][j] = (f32x4){0.f, 0.f, 0.f, 0.f};

    const int sw = (l15 >> 1) & 3;   // read-side swizzle term

    #pragma unroll
    for (int nn = 0; nn < NNZ; ++nn) {
        // chunk nn complete when only the 3 newest chunks remain outstanding
        if (nn < NNZ - 3)       asm volatile("s_waitcnt vmcnt(12)" ::: "memory");
        else if (nn == NNZ - 3) asm volatile("s_waitcnt vmcnt(8)"  ::: "memory");
        else if (nn == NNZ - 2) asm volatile("s_waitcnt vmcnt(4)"  ::: "memory");
        else                    asm volatile("s_waitcnt vmcnt(0)"  ::: "memory");

        const unsigned short* xb = lbase + (nn & 3) * 2048;
        #pragma unroll
        for (int mi = 0; mi < 4; ++mi) {
            const int rloc = mi * 16 + l15;
            short8 a = *(const short8*)&xb[rloc * 32 + ((quad ^ sw) * 8)];
            acc[mi][0] = __builtin_amdgcn_mfma_f32_16x16x32_bf16(a, wfrag[nn][0], acc[mi][0], 0, 0, 0);
            acc[mi][1] = __builtin_amdgcn_mfma_f32_16x16x32_bf16(a, wfrag[nn][1], acc[mi][1], 0, 0, 0);
        }
        // issue chunk nn+4 AFTER MFMAs: their lgkm waits guarantee the
        // slot's ds_reads (in-order LDS) completed -> no WAR hazard
        if (nn + 4 < NNZ) {
            const int p = nn + 4;
            const unsigned short* g = xsrc + cseq[p] * 32;
            #pragma unroll
            for (int j = 0; j < 4; ++j)
                GLD_LDS16(g + (size_t)j * 16 * XC, lbase + (p & 3) * 2048 + j * 512);
        }
    }

    // epilogue: C/D layout col=l15(=o), row=quad*4+reg(=m)
    const float b0v = bias[r * 32 + l15];
    const float b1v = bias[r * 32 + 16 + l15];
    #pragma unroll
    for (int mi = 0; mi < 4; ++mi) {
        const int rbase = row0 + wv * 64 + mi * 16 + quad * 4;
        #pragma unroll
        for (int reg = 0; reg < 4; ++reg) {
            float* op = out + (size_t)(rbase + reg) * XC + r * 32;
            op[l15]      = acc[mi][0][reg] + b0v;
            op[16 + l15] = acc[mi][1][reg] + b1v;
        }
    }
}

// ---- fallback (ws too small / unexpected shape): inline-conversion kernel ----
__global__ __launch_bounds__(256, 3) void bsl_fallback(
    const float* __restrict__ x, const int* __restrict__ crow,
    const int* __restrict__ cols, const float* __restrict__ wf,
    const float* __restrict__ mf, const float* __restrict__ bias,
    float* __restrict__ out)
{
    __shared__ unsigned short w_lds[NNZ][32][40];
    __shared__ unsigned short x_lds[MT][40];

    const int tid = threadIdx.x;
    const int bx  = blockIdx.x;
    const int r   = bx & 127;
    const int mt  = bx >> 7;
    const int row0 = mt * MT;
    const int start = crow[r];
    const int nnzr  = crow[r + 1] - start;

    const float4* wsrc = (const float4*)(wf + (size_t)start * 1024);
    const float4* msrc = (const float4*)(mf + (size_t)start * 1024);
    for (int i = tid; i < nnzr * 256; i += 256) {
        int nn = i >> 8, rem = i & 255;
        int o = rem >> 3, sg = rem & 7;
        float4 a = wsrc[i], b = msrc[i];
        *(uint2*)&w_lds[nn][o][sg * 4] =
            make_uint2(pk2(a.x * b.x, a.y * b.y), pk2(a.z * b.z, a.w * b.w));
    }

    const int lane = tid & 63;
    const int wv   = tid >> 6;
    const int l15  = lane & 15;
    const int quad = lane >> 4;

    f32x4 acc[4][2];
    #pragma unroll
    for (int i = 0; i < 4; ++i)
        #pragma unroll
        for (int j = 0; j < 2; ++j)
            acc[i][j] = (f32x4){0.f, 0.f, 0.f, 0.f};

    const int s4 = tid & 7;
    const int rr = tid >> 3;
    float4 v[8];
    {
        int c = cols[start];
        const float* xb = x + (size_t)(row0 + rr) * XC + c * 32 + s4 * 4;
        #pragma unroll
        for (int j = 0; j < 8; ++j) v[j] = *(const float4*)(xb + (size_t)j * 32 * XC);
    }

    for (int nn = 0; nn < nnzr; ++nn) {
        __syncthreads();
        #pragma unroll
        for (int j = 0; j < 8; ++j)
            *(uint2*)&x_lds[rr + j * 32][s4 * 4] =
                make_uint2(pk2(v[j].x, v[j].y), pk2(v[j].z, v[j].w));
        __syncthreads();

        if (nn + 1 < nnzr) {
            int c = cols[start + nn + 1];
            const float* xb = x + (size_t)(row0 + rr) * XC + c * 32 + s4 * 4;
            #pragma unroll
            for (int j = 0; j < 8; ++j) v[j] = *(const float4*)(xb + (size_t)j * 32 * XC);
        }

        short8 b0 = *(const short8*)&w_lds[nn][l15][quad * 8];
        short8 b1 = *(const short8*)&w_lds[nn][16 + l15][quad * 8];
        #pragma unroll
        for (int mi = 0; mi < 4; ++mi) {
            short8 a = *(const short8*)&x_lds[wv * 64 + mi * 16 + l15][quad * 8];
            acc[mi][0] = __builtin_amdgcn_mfma_f32_16x16x32_bf16(a, b0, acc[mi][0], 0, 0, 0);
            acc[mi][1] = __builtin_amdgcn_mfma_f32_16x16x32_bf16(a, b1, acc[mi][1], 0, 0, 0);
        }
    }

    const float b0v = bias[r * 32 + l15];
    const float b1v = bias[r * 32 + 16 + l15];
    #pragma unroll
    for (int mi = 0; mi < 4; ++mi) {
        const int rbase = row0 + wv * 64 + mi * 16 + quad * 4;
        #pragma unroll
        for (int reg = 0; reg < 4; ++reg) {
            float* op = out + (size_t)(rbase + reg) * XC + r * 32;
            op[l15]      = acc[mi][0][reg] + b0v;
            op[16 + l15] = acc[mi][1][reg] + b1v;
        }
    }
}

extern "C" void kernel_launch(void* const* d_in, const int* in_sizes, int n_in,
                              void* d_out, int out_size, void* d_ws, size_t ws_size,
                              hipStream_t stream) {
    const float* x      = (const float*)d_in[0];
    const int*   crow   = (const int*)d_in[1];
    const int*   cols   = (const int*)d_in[2];
    const float* mask   = (const float*)d_in[3];
    const float* weight = (const float*)d_in[4];
    const float* bias   = (const float*)d_in[5];
    float* out = (float*)d_out;

    const int xel   = in_sizes[0];        // 2048*4096
    const int wel   = in_sizes[4];        // 1664*1024
    const int rb    = in_sizes[1] - 1;    // 128
    const int batch = xel / XC;           // 2048

    const size_t xb_bytes = (size_t)xel * 2;
    const size_t wb_bytes = (size_t)wel * 2;

    // fast path requires batch == 2048 (mt = bx & 7 mapping assumes 8 tiles)
    const bool fast = (ws_size >= xb_bytes + wb_bytes) && (rb == 128) &&
                      (in_sizes[2] == rb * NNZ) && (batch == MT * 8);

    if (fast) {
        unsigned short* xbf = (unsigned short*)d_ws;
        unsigned short* wbf = (unsigned short*)((char*)d_ws + xb_bytes);
        int nx4 = xel / 4, nw4 = wel / 4;
        int tot = nx4 + nw4;
        prep<<<dim3((tot + 255) / 256), dim3(256), 0, stream>>>(x, weight, mask,
                                                                xbf, wbf, nx4, nw4);
        bsl_mfma2<<<dim3(rb * (batch / MT)), dim3(256), 0, stream>>>(xbf, cols, wbf,
                                                                     bias, out);
    } else {
        bsl_fallback<<<dim3(rb * (batch / MT)), dim3(256), 0, stream>>>(
            x, crow, cols, weight, mask, bias, out);
    }
}

// Round 7
// 121.549 us; speedup vs baseline: 1.0795x; 1.0182x over previous
//
#include <hip/hip_runtime.h>
#include <stdint.h>

#define XC 4096      // CB*BS
#define MT 256       // batch rows per workgroup (main path)
#define NNZ 13       // nnz blocks per row block (setup guarantees)

typedef __attribute__((ext_vector_type(8))) short short8;
typedef __attribute__((ext_vector_type(4))) float f32x4;

static __device__ __forceinline__ unsigned short f2bf(float f) {
    union { float f; unsigned int u; } c; c.f = f;
    unsigned int u = c.u;
    unsigned int r = 0x7FFFu + ((u >> 16) & 1u);
    return (unsigned short)((u + r) >> 16);
}
static __device__ __forceinline__ unsigned int pk2(float a, float b) {
    return (unsigned int)f2bf(a) | ((unsigned int)f2bf(b) << 16);
}

// async global->LDS, 16B per lane; LDS dest = uniform base + lane*16
#define GLD_LDS16(g, l) __builtin_amdgcn_global_load_lds(                      \
    (const __attribute__((address_space(1))) void*)(g),                        \
    (__attribute__((address_space(3))) void*)(l), 16, 0, 0)

// ---- prep: x fp32 -> bf16 (XCD-aligned), w*mask fp32 -> bf16 ----
// x-portion mapping: block bx (bx < nx4/256) with xcd = bx&7 converts the
// float4 slice [xcd*nx4/8 + (bx>>3)*256 + tid]. Slice k = rows
// [256k, 256k+256) = exactly the batch tile that main's mt = bx&7 = k
// blocks read on the SAME XCD -> bf16 writes stay resident in that XCD's
// write-back L2 (2 MB < 4 MB) and main's 13x chunk reuse hits L2 instead
// of fetching ~17 MB from L3/HBM.
__global__ void prep(const float* __restrict__ x, const float* __restrict__ w,
                     const float* __restrict__ m, unsigned short* __restrict__ xbf,
                     unsigned short* __restrict__ wbf, int nx4, int nw4) {
    const int bx = blockIdx.x;
    const int nxblocks = nx4 >> 8;          // 256 float4 per block
    if (bx < nxblocks) {
        const int per = nx4 >> 3;           // float4s per XCD slice
        const int i = (bx & 7) * per + (bx >> 3) * 256 + (int)threadIdx.x;
        float4 a = ((const float4*)x)[i];
        ((uint2*)xbf)[i] = make_uint2(pk2(a.x, a.y), pk2(a.z, a.w));
    } else {
        const int k = (bx - nxblocks) * 256 + (int)threadIdx.x;
        if (k < nw4) {
            float4 a = ((const float4*)w)[k];
            float4 b = ((const float4*)m)[k];
            ((uint2*)wbf)[k] = make_uint2(pk2(a.x * b.x, a.y * b.y),
                                          pk2(a.z * b.z, a.w * b.w));
        }
    }
}

// ---- main: barrier-free wave-private pipeline (round-3 best, unchanged) ----
// grid = 128 r-blocks * 8 batch tiles; 4 waves; wave owns 64 batch rows.
// w frags in VGPRs; x chunks triple-buffered in wave-private LDS via
// global_load_lds; sync = s_waitcnt vmcnt(N) only.
// XCD mapping: mt = bx & 7 pins one batch tile per XCD; with XCD-aligned
// prep the tile is already hot in that XCD's L2.
__global__ __launch_bounds__(256, 2) void bsl_mfma2(
    const unsigned short* __restrict__ xbf, const int* __restrict__ cols,
    const unsigned short* __restrict__ wbf, const float* __restrict__ bias,
    float* __restrict__ out)
{
    // 4 waves * 3 bufs * (64 rows * 32 shorts) = 48 KiB, XOR-swizzled
    __shared__ __align__(16) unsigned short x_lds[4 * 3 * 2048];

    const int tid  = threadIdx.x;
    const int bx   = blockIdx.x;
    const int mt   = bx & 7;      // XCD-pinned batch tile (grid = 128*8)
    const int r    = bx >> 3;
    const int row0 = mt * MT;
    const int start = r * NNZ;

    const int lane = tid & 63;
    const int wv   = tid >> 6;
    const int l15  = lane & 15;
    const int quad = lane >> 4;

    int cseq[NNZ];
    #pragma unroll
    for (int nn = 0; nn < NNZ; ++nn) cseq[nn] = cols[start + nn];

    // B frags: lane holds w[o = l15 (+16)][k = quad*8 + j]; coalesced 16B loads
    short8 wfrag[NNZ][2];
    {
        const unsigned short* wp0 = wbf + (size_t)start * 1024 + l15 * 32 + quad * 8;
        #pragma unroll
        for (int nn = 0; nn < NNZ; ++nn) {
            wfrag[nn][0] = *(const short8*)(wp0 + nn * 1024);
            wfrag[nn][1] = *(const short8*)(wp0 + nn * 1024 + 512);
        }
    }

    // staging geometry: lane covers row (j*16 + lane>>2), 16B unit
    // q = (lane&3) ^ ((lane>>3)&3)  (XOR swizzle; dest = base + lane*16)
    const int row0w = row0 + wv * 64;
    const int rl    = lane >> 2;
    const int qsw   = (lane & 3) ^ ((lane >> 3) & 3);
    const unsigned short* xsrc = xbf + ((size_t)row0w + rl) * XC + qsw * 8;
    unsigned short* lbase = &x_lds[wv * 6144];

    #pragma unroll
    for (int p = 0; p < 3; ++p) {   // issue chunks 0..2
        const unsigned short* g = xsrc + cseq[p] * 32;
        #pragma unroll
        for (int j = 0; j < 4; ++j)
            GLD_LDS16(g + (size_t)j * 16 * XC, lbase + p * 2048 + j * 512);
    }

    f32x4 acc[4][2];
    #pragma unroll
    for (int i = 0; i < 4; ++i)
        #pragma unroll
        for (int j = 0; j < 2; ++j)
            acc[i][j] = (f32x4){0.f, 0.f, 0.f, 0.f};

    const int sw = (l15 >> 1) & 3;   // read-side swizzle term

    #pragma unroll
    for (int nn = 0; nn < NNZ; ++nn) {
        // chunk nn complete when only the 2 newest chunks remain outstanding
        if (nn < NNZ - 2)       asm volatile("s_waitcnt vmcnt(8)" ::: "memory");
        else if (nn == NNZ - 2) asm volatile("s_waitcnt vmcnt(4)" ::: "memory");
        else                    asm volatile("s_waitcnt vmcnt(0)" ::: "memory");

        const unsigned short* xb = lbase + (nn % 3) * 2048;
        #pragma unroll
        for (int mi = 0; mi < 4; ++mi) {
            const int rloc = mi * 16 + l15;
            short8 a = *(const short8*)&xb[rloc * 32 + ((quad ^ sw) * 8)];
            acc[mi][0] = __builtin_amdgcn_mfma_f32_16x16x32_bf16(a, wfrag[nn][0], acc[mi][0], 0, 0, 0);
            acc[mi][1] = __builtin_amdgcn_mfma_f32_16x16x32_bf16(a, wfrag[nn][1], acc[mi][1], 0, 0, 0);
        }
        // issue chunk nn+3 AFTER MFMAs: their lgkm waits guarantee the
        // slot's ds_reads (in-order LDS) completed -> no WAR hazard
        if (nn + 3 < NNZ) {
            const int p = nn + 3;
            const unsigned short* g = xsrc + cseq[p] * 32;
            #pragma unroll
            for (int j = 0; j < 4; ++j)
                GLD_LDS16(g + (size_t)j * 16 * XC, lbase + (p % 3) * 2048 + j * 512);
        }
    }

    // epilogue: C/D layout col=l15(=o), row=quad*4+reg(=m)
    const float b0v = bias[r * 32 + l15];
    const float b1v = bias[r * 32 + 16 + l15];
    #pragma unroll
    for (int mi = 0; mi < 4; ++mi) {
        const int rbase = row0 + wv * 64 + mi * 16 + quad * 4;
        #pragma unroll
        for (int reg = 0; reg < 4; ++reg) {
            float* op = out + (size_t)(rbase + reg) * XC + r * 32;
            op[l15]      = acc[mi][0][reg] + b0v;
            op[16 + l15] = acc[mi][1][reg] + b1v;
        }
    }
}

// ---- fallback (ws too small / unexpected shape): inline-conversion kernel ----
__global__ __launch_bounds__(256, 3) void bsl_fallback(
    const float* __restrict__ x, const int* __restrict__ crow,
    const int* __restrict__ cols, const float* __restrict__ wf,
    const float* __restrict__ mf, const float* __restrict__ bias,
    float* __restrict__ out)
{
    __shared__ unsigned short w_lds[NNZ][32][40];
    __shared__ unsigned short x_lds[MT][40];

    const int tid = threadIdx.x;
    const int bx  = blockIdx.x;
    const int r   = bx & 127;
    const int mt  = bx >> 7;
    const int row0 = mt * MT;
    const int start = crow[r];
    const int nnzr  = crow[r + 1] - start;

    const float4* wsrc = (const float4*)(wf + (size_t)start * 1024);
    const float4* msrc = (const float4*)(mf + (size_t)start * 1024);
    for (int i = tid; i < nnzr * 256; i += 256) {
        int nn = i >> 8, rem = i & 255;
        int o = rem >> 3, sg = rem & 7;
        float4 a = wsrc[i], b = msrc[i];
        *(uint2*)&w_lds[nn][o][sg * 4] =
            make_uint2(pk2(a.x * b.x, a.y * b.y), pk2(a.z * b.z, a.w * b.w));
    }

    const int lane = tid & 63;
    const int wv   = tid >> 6;
    const int l15  = lane & 15;
    const int quad = lane >> 4;

    f32x4 acc[4][2];
    #pragma unroll
    for (int i = 0; i < 4; ++i)
        #pragma unroll
        for (int j = 0; j < 2; ++j)
            acc[i][j] = (f32x4){0.f, 0.f, 0.f, 0.f};

    const int s4 = tid & 7;
    const int rr = tid >> 3;
    float4 v[8];
    {
        int c = cols[start];
        const float* xb = x + (size_t)(row0 + rr) * XC + c * 32 + s4 * 4;
        #pragma unroll
        for (int j = 0; j < 8; ++j) v[j] = *(const float4*)(xb + (size_t)j * 32 * XC);
    }

    for (int nn = 0; nn < nnzr; ++nn) {
        __syncthreads();
        #pragma unroll
        for (int j = 0; j < 8; ++j)
            *(uint2*)&x_lds[rr + j * 32][s4 * 4] =
                make_uint2(pk2(v[j].x, v[j].y), pk2(v[j].z, v[j].w));
        __syncthreads();

        if (nn + 1 < nnzr) {
            int c = cols[start + nn + 1];
            const float* xb = x + (size_t)(row0 + rr) * XC + c * 32 + s4 * 4;
            #pragma unroll
            for (int j = 0; j < 8; ++j) v[j] = *(const float4*)(xb + (size_t)j * 32 * XC);
        }

        short8 b0 = *(const short8*)&w_lds[nn][l15][quad * 8];
        short8 b1 = *(const short8*)&w_lds[nn][16 + l15][quad * 8];
        #pragma unroll
        for (int mi = 0; mi < 4; ++mi) {
            short8 a = *(const short8*)&x_lds[wv * 64 + mi * 16 + l15][quad * 8];
            acc[mi][0] = __builtin_amdgcn_mfma_f32_16x16x32_bf16(a, b0, acc[mi][0], 0, 0, 0);
            acc[mi][1] = __builtin_amdgcn_mfma_f32_16x16x32_bf16(a, b1, acc[mi][1], 0, 0, 0);
        }
    }

    const float b0v = bias[r * 32 + l15];
    const float b1v = bias[r * 32 + 16 + l15];
    #pragma unroll
    for (int mi = 0; mi < 4; ++mi) {
        const int rbase = row0 + wv * 64 + mi * 16 + quad * 4;
        #pragma unroll
        for (int reg = 0; reg < 4; ++reg) {
            float* op = out + (size_t)(rbase + reg) * XC + r * 32;
            op[l15]      = acc[mi][0][reg] + b0v;
            op[16 + l15] = acc[mi][1][reg] + b1v;
        }
    }
}

extern "C" void kernel_launch(void* const* d_in, const int* in_sizes, int n_in,
                              void* d_out, int out_size, void* d_ws, size_t ws_size,
                              hipStream_t stream) {
    const float* x      = (const float*)d_in[0];
    const int*   crow   = (const int*)d_in[1];
    const int*   cols   = (const int*)d_in[2];
    const float* mask   = (const float*)d_in[3];
    const float* weight = (const float*)d_in[4];
    const float* bias   = (const float*)d_in[5];
    float* out = (float*)d_out;

    const int xel   = in_sizes[0];        // 2048*4096
    const int wel   = in_sizes[4];        // 1664*1024
    const int rb    = in_sizes[1] - 1;    // 128
    const int batch = xel / XC;           // 2048

    const size_t xb_bytes = (size_t)xel * 2;
    const size_t wb_bytes = (size_t)wel * 2;

    // fast path requires batch == 2048 (mt = bx & 7 mapping assumes 8 tiles)
    // and nx4 divisible by 2048 (XCD-aligned prep slicing)
    const int nx4 = xel / 4, nw4 = wel / 4;
    const bool fast = (ws_size >= xb_bytes + wb_bytes) && (rb == 128) &&
                      (in_sizes[2] == rb * NNZ) && (batch == MT * 8) &&
                      (nx4 % 2048 == 0);

    if (fast) {
        unsigned short* xbf = (unsigned short*)d_ws;
        unsigned short* wbf = (unsigned short*)((char*)d_ws + xb_bytes);
        const int nxblocks = nx4 / 256;
        const int nwblocks = (nw4 + 255) / 256;
        prep<<<dim3(nxblocks + nwblocks), dim3(256), 0, stream>>>(x, weight, mask,
                                                                  xbf, wbf, nx4, nw4);
        bsl_mfma2<<<dim3(rb * (batch / MT)), dim3(256), 0, stream>>>(xbf, cols, wbf,
                                                                     bias, out);
    } else {
        bsl_fallback<<<dim3(rb * (batch / MT)), dim3(256), 0, stream>>>(
            x, crow, cols, weight, mask, bias, out);
    }
}